// Round 2
// baseline (588.819 us; speedup 1.0000x reference)
//
#include <hip/hip_runtime.h>
#include <math.h>

typedef unsigned short u16;
typedef __attribute__((ext_vector_type(8))) short short8;   // 8 bf16 = one MFMA A/B frag
typedef __attribute__((ext_vector_type(4))) short short4v;  // 4 bf16
typedef __attribute__((ext_vector_type(4))) float f32x4;

__device__ __forceinline__ u16 f2b(float f) {   // f32 -> bf16 RNE
    unsigned u = __float_as_uint(f);
    u += 0x7fffu + ((u >> 16) & 1u);
    return (u16)(u >> 16);
}

__device__ __forceinline__ float b2f(u16 u) {
    return __uint_as_float(((unsigned)u) << 16);
}

__device__ __forceinline__ short8 cvt8(const f32x4* __restrict__ p) {
    f32x4 a = p[0], b = p[1];
    short8 r;
    r[0] = (short)f2b(a[0]); r[1] = (short)f2b(a[1]);
    r[2] = (short)f2b(a[2]); r[3] = (short)f2b(a[3]);
    r[4] = (short)f2b(b[0]); r[5] = (short)f2b(b[1]);
    r[6] = (short)f2b(b[2]); r[7] = (short)f2b(b[3]);
    return r;
}

// ---- prep: clear mark (word stores), build transposed bf16 weights:
//   WaT[c][k] = bf16(Wa[k][c])
//   WpT[c][k] = bf16(Wl[k][c] + Wl[134+k][c])   (p/q blocks of Wl cancel in me2[:E]+me2[E:])
__global__ __launch_bounds__(256) void k_prep(
    const float* __restrict__ Wa, const float* __restrict__ Wl,
    u16* __restrict__ WpT, u16* __restrict__ WaT,
    unsigned* __restrict__ markw, int nWords, int nbM)
{
    if ((int)blockIdx.x < nbM) {
        int i = (int)blockIdx.x * 256 + (int)threadIdx.x;
        if (i < nWords) markw[i] = 0u;
    } else {
        int c = ((int)blockIdx.x - nbM) * 2 + ((int)threadIdx.x >> 7);
        int k = threadIdx.x & 127;
        WaT[c * 128 + k] = f2b(Wa[k * 128 + c]);
        WpT[c * 128 + k] = f2b(Wl[k * 128 + c] + Wl[(134 + k) * 128 + c]);
    }
}

__global__ void k_mark(const int* __restrict__ eu, const int* __restrict__ ev,
                       unsigned char* __restrict__ mark, int NE)
{
    int i = blockIdx.x * 256 + threadIdx.x;
    if (i < NE) { mark[eu[i]] = 1; mark[ev[i]] = 1; }
}

// ---- per-vertex GEMM pass: one read of hv, two GEMMs.
//   mode bit0: compute+store mv_out[n] = mark ? elu(lrelu(hv@Wa + ba)) : 0
//   mode bit1: store YL fp32 = hv@Wp + bl   (bias folded so edge pass gets +2bl)
//   mode bit2: store YL bf16 = bf16(hv@Wp + bl)
__global__ __launch_bounds__(256) void k_vgemm(
    const float* __restrict__ hv,
    const u16* __restrict__ WpT, const u16* __restrict__ WaT,
    const float* __restrict__ bl, const float* __restrict__ ba,
    const unsigned char* __restrict__ mark,
    float* __restrict__ mv_out, float* __restrict__ yl32, u16* __restrict__ ylb,
    int NV, int mode)
{
    const int lane = threadIdx.x & 63;
    const int wv   = threadIdx.x >> 6;
    const int m = lane & 15, q = lane >> 4;
    const int n0 = (int)blockIdx.x * 64 + wv * 16;
    int nl = n0 + m; if (nl >= NV) nl = NV - 1;

    short8 a[4];
    {
        const f32x4* ap = (const f32x4*)(hv + (size_t)nl * 128 + q * 8);
        #pragma unroll
        for (int ks = 0; ks < 4; ++ks) a[ks] = cvt8(ap + ks * 8);
    }

    f32x4 accA[8], accP[8];
    #pragma unroll
    for (int t = 0; t < 8; ++t) {
        accA[t] = (f32x4){0.f, 0.f, 0.f, 0.f};
        accP[t] = (f32x4){0.f, 0.f, 0.f, 0.f};
    }

    const bool doA = (mode & 1) != 0;
    const bool doP = (mode & 6) != 0;

    #pragma unroll
    for (int ks = 0; ks < 4; ++ks) {
        #pragma unroll
        for (int t = 0; t < 8; ++t) {
            const size_t rowoff = (size_t)(t * 16 + m) * 128 + ks * 32 + q * 8;
            if (doA) {
                short8 bfr = *(const short8*)(WaT + rowoff);
                accA[t] = __builtin_amdgcn_mfma_f32_16x16x32_bf16(a[ks], bfr, accA[t], 0, 0, 0);
            }
            if (doP) {
                short8 bfr = *(const short8*)(WpT + rowoff);
                accP[t] = __builtin_amdgcn_mfma_f32_16x16x32_bf16(a[ks], bfr, accP[t], 0, 0, 0);
            }
        }
    }

    #pragma unroll
    for (int t = 0; t < 8; ++t) {
        const int col = t * 16 + m;
        if (doA) {
            const float bac = ba[col];
            #pragma unroll
            for (int i = 0; i < 4; ++i) {
                const int row = n0 + q * 4 + i;
                if (row < NV) {
                    float z = accA[t][i] + bac;
                    float y = (z > 0.f) ? z : 0.01f * z;          // leaky_relu
                    float r = (y > 0.f) ? y : (__expf(y) - 1.f);  // elu
                    if (mark[row] == 0) r = 0.f;                  // empty segment -> elu(0)=0
                    __builtin_nontemporal_store(r, &mv_out[(size_t)row * 128 + col]);
                }
            }
        }
        if (mode & 2) {
            const float blc = bl[col];
            #pragma unroll
            for (int i = 0; i < 4; ++i) {
                const int row = n0 + q * 4 + i;
                if (row < NV) yl32[(size_t)row * 128 + col] = accP[t][i] + blc;  // cached: edge pass reads it
            }
        }
        if (mode & 4) {
            const float blc = bl[col];
            #pragma unroll
            for (int i = 0; i < 4; ++i) {
                const int row = n0 + q * 4 + i;
                if (row < NV) ylb[(size_t)row * 128 + col] = f2b(accP[t][i] + blc);
            }
        }
    }
}

// ---- edge pass (fp32 YL): me[e] = lrelu(YL[u] + YL[v])  (biases already folded in)
// Per wave: 16 edges, 2 per round. 32 lanes cover one 512B row: gathers are
// 2x512B contiguous segments per instruction; stores are fully coalesced 1KB NT dwordx4.
__global__ __launch_bounds__(256) void k_edge_f32(
    const float* __restrict__ yl, const int* __restrict__ eu, const int* __restrict__ ev,
    float* __restrict__ me, int NE)
{
    const int lane = threadIdx.x & 63;
    const int wv   = threadIdx.x >> 6;
    const int half = lane >> 5;          // which edge of the pair
    const int c4   = (lane & 31) << 2;   // starting float column
    const int e0   = (int)blockIdx.x * 64 + wv * 16;

    int iu[8], iv[8];
    #pragma unroll
    for (int j = 0; j < 8; ++j) {
        int e = e0 + 2 * j + half; if (e >= NE) e = NE - 1;
        iu[j] = eu[e]; iv[j] = ev[e];
    }
    f32x4 ru[8], rv[8];
    #pragma unroll
    for (int j = 0; j < 8; ++j) {
        ru[j] = *(const f32x4*)(yl + (size_t)iu[j] * 128 + c4);
        rv[j] = *(const f32x4*)(yl + (size_t)iv[j] * 128 + c4);
    }
    #pragma unroll
    for (int j = 0; j < 8; ++j) {
        int e = e0 + 2 * j + half;
        if (e < NE) {
            f32x4 o;
            #pragma unroll
            for (int i = 0; i < 4; ++i) {
                float x = ru[j][i] + rv[j][i];
                o[i] = (x > 0.f) ? x : 0.01f * x;
            }
            __builtin_nontemporal_store(o, (f32x4*)(me + (size_t)e * 128 + c4));
        }
    }
}

// ---- edge pass (bf16 YL fallback): halves gather traffic, +~0.005 abs error
__global__ __launch_bounds__(256) void k_edge_b16(
    const u16* __restrict__ ylb, const int* __restrict__ eu, const int* __restrict__ ev,
    float* __restrict__ me, int NE)
{
    const int lane = threadIdx.x & 63;
    const int wv   = threadIdx.x >> 6;
    const int half = lane >> 5;
    const int c4   = (lane & 31) << 2;   // starting bf16 column
    const int e0   = (int)blockIdx.x * 64 + wv * 16;

    int iu[8], iv[8];
    #pragma unroll
    for (int j = 0; j < 8; ++j) {
        int e = e0 + 2 * j + half; if (e >= NE) e = NE - 1;
        iu[j] = eu[e]; iv[j] = ev[e];
    }
    short4v ru[8], rv[8];
    #pragma unroll
    for (int j = 0; j < 8; ++j) {
        ru[j] = *(const short4v*)(ylb + (size_t)iu[j] * 128 + c4);
        rv[j] = *(const short4v*)(ylb + (size_t)iv[j] * 128 + c4);
    }
    #pragma unroll
    for (int j = 0; j < 8; ++j) {
        int e = e0 + 2 * j + half;
        if (e < NE) {
            f32x4 o;
            #pragma unroll
            for (int i = 0; i < 4; ++i) {
                float x = b2f((u16)ru[j][i]) + b2f((u16)rv[j][i]);
                o[i] = (x > 0.f) ? x : 0.01f * x;
            }
            __builtin_nontemporal_store(o, (f32x4*)(me + (size_t)e * 128 + c4));
        }
    }
}

extern "C" void kernel_launch(void* const* d_in, const int* in_sizes, int n_in,
                              void* d_out, int out_size, void* d_ws, size_t ws_size,
                              hipStream_t stream)
{
    // inputs: 0 hv,1 he,2 p,3 q,4 edge_u,5 edge_v,6 Wa,7 ba,8 Wal,9 bal,10 Wl,11 bl
    const float* hv = (const float*)d_in[0];
    const int*   eu = (const int*)d_in[4];
    const int*   ev = (const int*)d_in[5];
    const float* Wa = (const float*)d_in[6];
    const float* ba = (const float*)d_in[7];
    const float* Wl = (const float*)d_in[10];
    const float* bl = (const float*)d_in[11];

    const int NV = in_sizes[0] / 128;   // 50000
    const int NE = in_sizes[4];         // 400000

    float* mv_out = (float*)d_out;
    float* me_out = mv_out + (size_t)NV * 128;

    // workspace layout: WpT(32KB) | WaT(32KB) | mark(NV, padded) | YL
    u16* WpT = (u16*)d_ws;
    u16* WaT = WpT + 128 * 128;
    unsigned char* mark = (unsigned char*)(WaT + 128 * 128);
    const size_t ylOff = 65536 + (((size_t)NV + 255) & ~(size_t)255);

    const int nWords = (NV + 3) / 4;
    const int nbM = (nWords + 255) / 256;
    int nbV = (NV + 63) / 64; if (nbV < 1) nbV = 1;
    int nbE = (NE + 63) / 64; if (nbE < 1) nbE = 1;

    k_prep<<<nbM + 64, 256, 0, stream>>>(Wa, Wl, WpT, WaT, (unsigned*)mark, nWords, nbM);
    k_mark<<<(NE + 255) / 256, 256, 0, stream>>>(eu, ev, mark, NE);

    if (ws_size >= ylOff + (size_t)NV * 512) {
        // primary: fp32 YL in workspace (25.6 MB) — identical numerics to the MFMA edge path
        float* yl32 = (float*)((char*)d_ws + ylOff);
        k_vgemm<<<nbV, 256, 0, stream>>>(hv, WpT, WaT, bl, ba, mark,
                                         mv_out, yl32, nullptr, NV, 1 | 2);
        k_edge_f32<<<nbE, 256, 0, stream>>>(yl32, eu, ev, me_out, NE);
    } else if (ws_size >= ylOff + (size_t)NV * 256) {
        // bf16 YL in workspace (12.8 MB)
        u16* ylb = (u16*)((char*)d_ws + ylOff);
        k_vgemm<<<nbV, 256, 0, stream>>>(hv, WpT, WaT, bl, ba, mark,
                                         mv_out, nullptr, ylb, NV, 1 | 4);
        k_edge_b16<<<nbE, 256, 0, stream>>>(ylb, eu, ev, me_out, NE);
    } else {
        // minimal ws: stage bf16 YL in the (not yet written) mv region; write mv last.
        u16* ylb = (u16*)mv_out;            // 12.8 MB <= 25.6 MB region
        k_vgemm<<<nbV, 256, 0, stream>>>(hv, WpT, WaT, bl, ba, mark,
                                         nullptr, nullptr, ylb, NV, 4);
        k_edge_b16<<<nbE, 256, 0, stream>>>(ylb, eu, ev, me_out, NE);
        k_vgemm<<<nbV, 256, 0, stream>>>(hv, WpT, WaT, bl, ba, mark,
                                         mv_out, nullptr, nullptr, NV, 1);
    }
}

// Round 3
// 401.210 us; speedup vs baseline: 1.4676x; 1.4676x over previous
//
#include <hip/hip_runtime.h>
#include <math.h>

typedef unsigned short u16;
typedef __attribute__((ext_vector_type(8))) short short8;   // 8 bf16 = one MFMA A/B frag
typedef __attribute__((ext_vector_type(4))) short short4v;  // 4 bf16
typedef __attribute__((ext_vector_type(4))) float f32x4;

__device__ __forceinline__ u16 f2b(float f) {   // f32 -> bf16 RNE
    unsigned u = __float_as_uint(f);
    u += 0x7fffu + ((u >> 16) & 1u);
    return (u16)(u >> 16);
}

__device__ __forceinline__ float b2f(u16 u) {
    return __uint_as_float(((unsigned)u) << 16);
}

__device__ __forceinline__ short8 cvt8(const f32x4* __restrict__ p) {
    f32x4 a = p[0], b = p[1];
    short8 r;
    r[0] = (short)f2b(a[0]); r[1] = (short)f2b(a[1]);
    r[2] = (short)f2b(a[2]); r[3] = (short)f2b(a[3]);
    r[4] = (short)f2b(b[0]); r[5] = (short)f2b(b[1]);
    r[6] = (short)f2b(b[2]); r[7] = (short)f2b(b[3]);
    return r;
}

// ---- prep: clear mark (word stores), build transposed bf16 weights:
//   WaT[c][k] = bf16(Wa[k][c])
//   WpT[c][k] = bf16(Wl[k][c] + Wl[134+k][c])   (p/q blocks of Wl cancel in me2[:E]+me2[E:])
__global__ __launch_bounds__(256) void k_prep(
    const float* __restrict__ Wa, const float* __restrict__ Wl,
    u16* __restrict__ WpT, u16* __restrict__ WaT,
    unsigned* __restrict__ markw, int nWords, int nbM)
{
    if ((int)blockIdx.x < nbM) {
        int i = (int)blockIdx.x * 256 + (int)threadIdx.x;
        if (i < nWords) markw[i] = 0u;
    } else {
        int c = ((int)blockIdx.x - nbM) * 2 + ((int)threadIdx.x >> 7);
        int k = threadIdx.x & 127;
        WaT[c * 128 + k] = f2b(Wa[k * 128 + c]);
        WpT[c * 128 + k] = f2b(Wl[k * 128 + c] + Wl[(134 + k) * 128 + c]);
    }
}

__global__ void k_mark(const int* __restrict__ eu, const int* __restrict__ ev,
                       unsigned char* __restrict__ mark, int NE)
{
    int i = blockIdx.x * 256 + threadIdx.x;
    if (i < NE) { mark[eu[i]] = 1; mark[ev[i]] = 1; }
}

// ---- per-vertex GEMM body, COMPILE-TIME specialized (one acc set, one weight
// stream, one store path per instantiation — keeps the proven 64-VGPR codegen).
//   MODE 0: mv_out[n] = mark ? elu(lrelu(hv@WaT + ba)) : 0   (NT scalar stores)
//   MODE 1: yl32[n]  = hv@WpT + bl                           (fp32, edge pass reads it)
//   MODE 2: ylb[n]   = bf16(hv@WpT + bl)
template<int MODE>
__device__ __forceinline__ void vgemm_body(
    const float* __restrict__ hv, const u16* __restrict__ WT,
    const float* __restrict__ bias, const unsigned char* __restrict__ mark,
    float* __restrict__ out32, u16* __restrict__ outb,
    int NV, int blk)
{
    const int lane = threadIdx.x & 63;
    const int wv   = threadIdx.x >> 6;
    const int m = lane & 15, q = lane >> 4;
    const int n0 = blk * 64 + wv * 16;
    int nl = n0 + m; if (nl >= NV) nl = NV - 1;

    short8 a[4];
    {
        const f32x4* ap = (const f32x4*)(hv + (size_t)nl * 128 + q * 8);
        #pragma unroll
        for (int ks = 0; ks < 4; ++ks) a[ks] = cvt8(ap + ks * 8);
    }

    f32x4 acc[8];
    #pragma unroll
    for (int t = 0; t < 8; ++t) acc[t] = (f32x4){0.f, 0.f, 0.f, 0.f};

    #pragma unroll
    for (int ks = 0; ks < 4; ++ks) {
        #pragma unroll
        for (int t = 0; t < 8; ++t) {
            short8 b = *(const short8*)(WT + (size_t)(t * 16 + m) * 128 + ks * 32 + q * 8);
            acc[t] = __builtin_amdgcn_mfma_f32_16x16x32_bf16(a[ks], b, acc[t], 0, 0, 0);
        }
    }

    #pragma unroll
    for (int t = 0; t < 8; ++t) {
        const int col = t * 16 + m;
        const float bc = bias[col];
        #pragma unroll
        for (int i = 0; i < 4; ++i) {
            const int row = n0 + q * 4 + i;
            if (row < NV) {
                float z = acc[t][i] + bc;
                if (MODE == 0) {
                    float y = (z > 0.f) ? z : 0.01f * z;          // leaky_relu
                    float r = (y > 0.f) ? y : (__expf(y) - 1.f);  // elu
                    if (mark[row] == 0) r = 0.f;                  // empty segment -> elu(0)=0
                    __builtin_nontemporal_store(r, &out32[(size_t)row * 128 + col]);
                } else if (MODE == 1) {
                    out32[(size_t)row * 128 + col] = z;           // cached: edge pass reads it
                } else {
                    outb[(size_t)row * 128 + col] = f2b(z);
                }
            }
        }
    }
}

// fused vertex pass: blocks [0,nbV) do mv, blocks [nbV,2nbV) do YL fp32.
// Disjoint per-block branches, each self-contained — same structure as the
// proven 64-VGPR k_main.
__global__ __launch_bounds__(256) void k_vert(
    const float* __restrict__ hv,
    const u16* __restrict__ WpT, const u16* __restrict__ WaT,
    const float* __restrict__ bl, const float* __restrict__ ba,
    const unsigned char* __restrict__ mark,
    float* __restrict__ mv_out, float* __restrict__ yl32,
    int NV, int nbV)
{
    if ((int)blockIdx.x < nbV)
        vgemm_body<0>(hv, WaT, ba, mark, mv_out, nullptr, NV, (int)blockIdx.x);
    else
        vgemm_body<1>(hv, WpT, bl, nullptr, yl32, nullptr, NV, (int)blockIdx.x - nbV);
}

// standalone variants for the small-ws fallbacks
__global__ __launch_bounds__(256) void k_vmv(
    const float* __restrict__ hv, const u16* __restrict__ WaT,
    const float* __restrict__ ba, const unsigned char* __restrict__ mark,
    float* __restrict__ mv_out, int NV)
{
    vgemm_body<0>(hv, WaT, ba, mark, mv_out, nullptr, NV, (int)blockIdx.x);
}

__global__ __launch_bounds__(256) void k_vylb(
    const float* __restrict__ hv, const u16* __restrict__ WpT,
    const float* __restrict__ bl, u16* __restrict__ ylb, int NV)
{
    vgemm_body<2>(hv, WpT, bl, nullptr, nullptr, ylb, NV, (int)blockIdx.x);
}

// ---- edge pass (fp32 YL): me[e] = lrelu(YL[u] + YL[v])  (biases already folded in)
// Per wave: 16 edges, 2 per round. 32 lanes cover one 512B row: gathers are
// 2x512B contiguous segments per instruction; stores are fully coalesced 1KB NT dwordx4.
__global__ __launch_bounds__(256) void k_edge_f32(
    const float* __restrict__ yl, const int* __restrict__ eu, const int* __restrict__ ev,
    float* __restrict__ me, int NE)
{
    const int lane = threadIdx.x & 63;
    const int wv   = threadIdx.x >> 6;
    const int half = lane >> 5;          // which edge of the pair
    const int c4   = (lane & 31) << 2;   // starting float column
    const int e0   = (int)blockIdx.x * 64 + wv * 16;

    int iu[8], iv[8];
    #pragma unroll
    for (int j = 0; j < 8; ++j) {
        int e = e0 + 2 * j + half; if (e >= NE) e = NE - 1;
        iu[j] = eu[e]; iv[j] = ev[e];
    }
    f32x4 ru[8], rv[8];
    #pragma unroll
    for (int j = 0; j < 8; ++j) {
        ru[j] = *(const f32x4*)(yl + (size_t)iu[j] * 128 + c4);
        rv[j] = *(const f32x4*)(yl + (size_t)iv[j] * 128 + c4);
    }
    #pragma unroll
    for (int j = 0; j < 8; ++j) {
        int e = e0 + 2 * j + half;
        if (e < NE) {
            f32x4 o;
            #pragma unroll
            for (int i = 0; i < 4; ++i) {
                float x = ru[j][i] + rv[j][i];
                o[i] = (x > 0.f) ? x : 0.01f * x;
            }
            __builtin_nontemporal_store(o, (f32x4*)(me + (size_t)e * 128 + c4));
        }
    }
}

// ---- edge pass (bf16 YL fallback): halves gather traffic
__global__ __launch_bounds__(256) void k_edge_b16(
    const u16* __restrict__ ylb, const int* __restrict__ eu, const int* __restrict__ ev,
    float* __restrict__ me, int NE)
{
    const int lane = threadIdx.x & 63;
    const int wv   = threadIdx.x >> 6;
    const int half = lane >> 5;
    const int c4   = (lane & 31) << 2;   // starting bf16 column
    const int e0   = (int)blockIdx.x * 64 + wv * 16;

    int iu[8], iv[8];
    #pragma unroll
    for (int j = 0; j < 8; ++j) {
        int e = e0 + 2 * j + half; if (e >= NE) e = NE - 1;
        iu[j] = eu[e]; iv[j] = ev[e];
    }
    short4v ru[8], rv[8];
    #pragma unroll
    for (int j = 0; j < 8; ++j) {
        ru[j] = *(const short4v*)(ylb + (size_t)iu[j] * 128 + c4);
        rv[j] = *(const short4v*)(ylb + (size_t)iv[j] * 128 + c4);
    }
    #pragma unroll
    for (int j = 0; j < 8; ++j) {
        int e = e0 + 2 * j + half;
        if (e < NE) {
            f32x4 o;
            #pragma unroll
            for (int i = 0; i < 4; ++i) {
                float x = b2f((u16)ru[j][i]) + b2f((u16)rv[j][i]);
                o[i] = (x > 0.f) ? x : 0.01f * x;
            }
            __builtin_nontemporal_store(o, (f32x4*)(me + (size_t)e * 128 + c4));
        }
    }
}

extern "C" void kernel_launch(void* const* d_in, const int* in_sizes, int n_in,
                              void* d_out, int out_size, void* d_ws, size_t ws_size,
                              hipStream_t stream)
{
    // inputs: 0 hv,1 he,2 p,3 q,4 edge_u,5 edge_v,6 Wa,7 ba,8 Wal,9 bal,10 Wl,11 bl
    const float* hv = (const float*)d_in[0];
    const int*   eu = (const int*)d_in[4];
    const int*   ev = (const int*)d_in[5];
    const float* Wa = (const float*)d_in[6];
    const float* ba = (const float*)d_in[7];
    const float* Wl = (const float*)d_in[10];
    const float* bl = (const float*)d_in[11];

    const int NV = in_sizes[0] / 128;   // 50000
    const int NE = in_sizes[4];         // 400000

    float* mv_out = (float*)d_out;
    float* me_out = mv_out + (size_t)NV * 128;

    // workspace layout: WpT(32KB) | WaT(32KB) | mark(NV, padded) | YL
    u16* WpT = (u16*)d_ws;
    u16* WaT = WpT + 128 * 128;
    unsigned char* mark = (unsigned char*)(WaT + 128 * 128);
    const size_t ylOff = 65536 + (((size_t)NV + 255) & ~(size_t)255);

    const int nWords = (NV + 3) / 4;
    const int nbM = (nWords + 255) / 256;
    int nbV = (NV + 63) / 64; if (nbV < 1) nbV = 1;
    int nbE = (NE + 63) / 64; if (nbE < 1) nbE = 1;

    k_prep<<<nbM + 64, 256, 0, stream>>>(Wa, Wl, WpT, WaT, (unsigned*)mark, nWords, nbM);
    k_mark<<<(NE + 255) / 256, 256, 0, stream>>>(eu, ev, mark, NE);

    if (ws_size >= ylOff + (size_t)NV * 512) {
        // primary: fp32 YL in workspace (25.6 MB) — same numerics as the MFMA edge path
        float* yl32 = (float*)((char*)d_ws + ylOff);
        k_vert<<<2 * nbV, 256, 0, stream>>>(hv, WpT, WaT, bl, ba, mark,
                                            mv_out, yl32, NV, nbV);
        k_edge_f32<<<nbE, 256, 0, stream>>>(yl32, eu, ev, me_out, NE);
    } else if (ws_size >= ylOff + (size_t)NV * 256) {
        // bf16 YL in workspace (12.8 MB)
        u16* ylb = (u16*)((char*)d_ws + ylOff);
        k_vmv<<<nbV, 256, 0, stream>>>(hv, WaT, ba, mark, mv_out, NV);
        k_vylb<<<nbV, 256, 0, stream>>>(hv, WpT, bl, ylb, NV);
        k_edge_b16<<<nbE, 256, 0, stream>>>(ylb, eu, ev, me_out, NE);
    } else {
        // minimal ws: stage bf16 YL in the (not yet written) mv region; write mv last.
        u16* ylb = (u16*)mv_out;            // 12.8 MB <= 25.6 MB region
        k_vylb<<<nbV, 256, 0, stream>>>(hv, WpT, bl, ylb, NV);
        k_edge_b16<<<nbE, 256, 0, stream>>>(ylb, eu, ev, me_out, NE);
        k_vmv<<<nbV, 256, 0, stream>>>(hv, WaT, ba, mark, mv_out, NV);
    }
}

// Round 4
// 366.404 us; speedup vs baseline: 1.6070x; 1.0950x over previous
//
#include <hip/hip_runtime.h>
#include <math.h>

typedef unsigned short u16;
typedef __attribute__((ext_vector_type(8))) short short8;   // 8 bf16 = one MFMA A/B frag
typedef __attribute__((ext_vector_type(4))) short short4v;  // 4 fp16
typedef __attribute__((ext_vector_type(4))) float f32x4;

__device__ __forceinline__ u16 f2b(float f) {   // f32 -> bf16 RNE
    unsigned u = __float_as_uint(f);
    u += 0x7fffu + ((u >> 16) & 1u);
    return (u16)(u >> 16);
}

__device__ __forceinline__ u16 f2h(float f) {   // f32 -> fp16 RNE
    _Float16 h = (_Float16)f;
    return __builtin_bit_cast(u16, h);
}

__device__ __forceinline__ float h2f(short s) { // fp16 -> f32
    _Float16 h = __builtin_bit_cast(_Float16, s);
    return (float)h;
}

__device__ __forceinline__ short8 cvt8(const f32x4* __restrict__ p) {
    f32x4 a = p[0], b = p[1];
    short8 r;
    r[0] = (short)f2b(a[0]); r[1] = (short)f2b(a[1]);
    r[2] = (short)f2b(a[2]); r[3] = (short)f2b(a[3]);
    r[4] = (short)f2b(b[0]); r[5] = (short)f2b(b[1]);
    r[6] = (short)f2b(b[2]); r[7] = (short)f2b(b[3]);
    return r;
}

// ---- prep: clear mark (word stores), build transposed bf16 weights:
//   WaT[c][k] = bf16(Wa[k][c])
//   WpT[c][k] = bf16(Wl[k][c] + Wl[134+k][c])   (p/q blocks of Wl cancel in me2[:E]+me2[E:])
__global__ __launch_bounds__(256) void k_prep(
    const float* __restrict__ Wa, const float* __restrict__ Wl,
    u16* __restrict__ WpT, u16* __restrict__ WaT,
    unsigned* __restrict__ markw, int nWords, int nbM)
{
    if ((int)blockIdx.x < nbM) {
        int i = (int)blockIdx.x * 256 + (int)threadIdx.x;
        if (i < nWords) markw[i] = 0u;
    } else {
        int c = ((int)blockIdx.x - nbM) * 2 + ((int)threadIdx.x >> 7);
        int k = threadIdx.x & 127;
        WaT[c * 128 + k] = f2b(Wa[k * 128 + c]);
        WpT[c * 128 + k] = f2b(Wl[k * 128 + c] + Wl[(134 + k) * 128 + c]);
    }
}

__global__ void k_mark(const int* __restrict__ eu, const int* __restrict__ ev,
                       unsigned char* __restrict__ mark, int NE)
{
    int i = blockIdx.x * 256 + threadIdx.x;
    if (i < NE) { mark[eu[i]] = 1; mark[ev[i]] = 1; }
}

// ---- per-vertex GEMM body, COMPILE-TIME specialized (one acc set, one weight
// stream, one store path per instantiation — proven 64-VGPR codegen).
//   MODE 0: mv_out[n] = mark ? elu(lrelu(hv@WaT + ba)) : 0   (NT stores)
//   MODE 3: ylh[n]   = fp16(hv@WpT + bl)                     (cached: edge pass reads it)
template<int MODE>
__device__ __forceinline__ void vgemm_body(
    const float* __restrict__ hv, const u16* __restrict__ WT,
    const float* __restrict__ bias, const unsigned char* __restrict__ mark,
    float* __restrict__ out32, u16* __restrict__ outh,
    int NV, int blk)
{
    const int lane = threadIdx.x & 63;
    const int wv   = threadIdx.x >> 6;
    const int m = lane & 15, q = lane >> 4;
    const int n0 = blk * 64 + wv * 16;
    int nl = n0 + m; if (nl >= NV) nl = NV - 1;

    short8 a[4];
    {
        const f32x4* ap = (const f32x4*)(hv + (size_t)nl * 128 + q * 8);
        #pragma unroll
        for (int ks = 0; ks < 4; ++ks) a[ks] = cvt8(ap + ks * 8);
    }

    f32x4 acc[8];
    #pragma unroll
    for (int t = 0; t < 8; ++t) acc[t] = (f32x4){0.f, 0.f, 0.f, 0.f};

    #pragma unroll
    for (int ks = 0; ks < 4; ++ks) {
        #pragma unroll
        for (int t = 0; t < 8; ++t) {
            short8 b = *(const short8*)(WT + (size_t)(t * 16 + m) * 128 + ks * 32 + q * 8);
            acc[t] = __builtin_amdgcn_mfma_f32_16x16x32_bf16(a[ks], b, acc[t], 0, 0, 0);
        }
    }

    #pragma unroll
    for (int t = 0; t < 8; ++t) {
        const int col = t * 16 + m;
        const float bc = bias[col];
        #pragma unroll
        for (int i = 0; i < 4; ++i) {
            const int row = n0 + q * 4 + i;
            if (row < NV) {
                float z = acc[t][i] + bc;
                if (MODE == 0) {
                    float y = (z > 0.f) ? z : 0.01f * z;          // leaky_relu
                    float r = (y > 0.f) ? y : (__expf(y) - 1.f);  // elu
                    if (mark[row] == 0) r = 0.f;                  // empty segment -> elu(0)=0
                    __builtin_nontemporal_store(r, &out32[(size_t)row * 128 + col]);
                } else {
                    outh[(size_t)row * 128 + col] = f2h(z);       // regular store: keep in L2/L3
                }
            }
        }
    }
}

// YL (fp16) pass
__global__ __launch_bounds__(256) void k_vyl16(
    const float* __restrict__ hv, const u16* __restrict__ WpT,
    const float* __restrict__ bl, u16* __restrict__ ylh, int NV)
{
    vgemm_body<3>(hv, WpT, bl, nullptr, nullptr, ylh, NV, (int)blockIdx.x);
}

// ---- edge body (fp16 YL): me[e] = lrelu(YL[u] + YL[v])  (biases folded: YL has +bl each)
// Per wave: 16 edges, 2 per round. 32 lanes cover one row: gathers are 2x256B
// contiguous segments per instruction; stores fully coalesced 2x512B NT dwordx4.
__device__ __forceinline__ void edge_body(
    const u16* __restrict__ ylh, const int* __restrict__ eu, const int* __restrict__ ev,
    float* __restrict__ me, int NE, int blk)
{
    const int lane = threadIdx.x & 63;
    const int wv   = threadIdx.x >> 6;
    const int half = lane >> 5;          // which edge of the pair
    const int c4   = (lane & 31) << 2;   // starting column (4 per lane)
    const int e0   = blk * 64 + wv * 16;

    int iu[8], iv[8];
    #pragma unroll
    for (int j = 0; j < 8; ++j) {
        int e = e0 + 2 * j + half; if (e >= NE) e = NE - 1;
        iu[j] = eu[e]; iv[j] = ev[e];
    }
    short4v ru[8], rv[8];
    #pragma unroll
    for (int j = 0; j < 8; ++j) {
        ru[j] = *(const short4v*)(ylh + (size_t)iu[j] * 128 + c4);
        rv[j] = *(const short4v*)(ylh + (size_t)iv[j] * 128 + c4);
    }
    #pragma unroll
    for (int j = 0; j < 8; ++j) {
        int e = e0 + 2 * j + half;
        if (e < NE) {
            f32x4 o;
            #pragma unroll
            for (int i = 0; i < 4; ++i) {
                float x = h2f(ru[j][i]) + h2f(rv[j][i]);
                o[i] = (x > 0.f) ? x : 0.01f * x;
            }
            __builtin_nontemporal_store(o, (f32x4*)(me + (size_t)e * 128 + c4));
        }
    }
}

// ---- mixed kernel: nbE edge blocks + nbV mv blocks, RATE-INTERLEAVED so the
// compute-bound mv GEMM fills CU issue slots while edge blocks wait on gathers.
// Block b is an mv block iff floor((b+1)*nbV/T) > floor(b*nbV/T); products fit 32-bit.
// Degenerate forms: nbV=0 -> pure edge grid; nbE=0 -> pure mv grid (fallback path).
__global__ __launch_bounds__(256) void k_mixed(
    const u16* __restrict__ ylh, const int* __restrict__ eu, const int* __restrict__ ev,
    const float* __restrict__ hv, const u16* __restrict__ WaT,
    const float* __restrict__ ba, const unsigned char* __restrict__ mark,
    float* __restrict__ mv_out, float* __restrict__ me_out,
    int NE, int NV, int nbE, int nbV)
{
    const unsigned b = blockIdx.x;
    const unsigned T = (unsigned)nbE + (unsigned)nbV;
    const unsigned q0 = (b * (unsigned)nbV) / T;
    const unsigned q1 = ((b + 1u) * (unsigned)nbV) / T;
    if (q1 > q0)
        vgemm_body<0>(hv, WaT, ba, mark, mv_out, nullptr, NV, (int)q0);
    else
        edge_body(ylh, eu, ev, me_out, NE, (int)(b - q0));
}

extern "C" void kernel_launch(void* const* d_in, const int* in_sizes, int n_in,
                              void* d_out, int out_size, void* d_ws, size_t ws_size,
                              hipStream_t stream)
{
    // inputs: 0 hv,1 he,2 p,3 q,4 edge_u,5 edge_v,6 Wa,7 ba,8 Wal,9 bal,10 Wl,11 bl
    const float* hv = (const float*)d_in[0];
    const int*   eu = (const int*)d_in[4];
    const int*   ev = (const int*)d_in[5];
    const float* Wa = (const float*)d_in[6];
    const float* ba = (const float*)d_in[7];
    const float* Wl = (const float*)d_in[10];
    const float* bl = (const float*)d_in[11];

    const int NV = in_sizes[0] / 128;   // 50000
    const int NE = in_sizes[4];         // 400000

    float* mv_out = (float*)d_out;
    float* me_out = mv_out + (size_t)NV * 128;

    // workspace layout: WpT(32KB) | WaT(32KB) | mark(NV, padded) | YL fp16 (NV*256B)
    u16* WpT = (u16*)d_ws;
    u16* WaT = WpT + 128 * 128;
    unsigned char* mark = (unsigned char*)(WaT + 128 * 128);
    const size_t ylOff = 65536 + (((size_t)NV + 255) & ~(size_t)255);

    const int nWords = (NV + 3) / 4;
    const int nbM = (nWords + 255) / 256;
    int nbV = (NV + 63) / 64; if (nbV < 1) nbV = 1;
    int nbE = (NE + 63) / 64; if (nbE < 1) nbE = 1;

    k_prep<<<nbM + 64, 256, 0, stream>>>(Wa, Wl, WpT, WaT, (unsigned*)mark, nWords, nbM);
    k_mark<<<(NE + 255) / 256, 256, 0, stream>>>(eu, ev, mark, NE);

    if (ws_size >= ylOff + (size_t)NV * 256) {
        // primary: fp16 YL in workspace (12.8 MB), mv interleaved into the edge grid
        u16* ylh = (u16*)((char*)d_ws + ylOff);
        k_vyl16<<<nbV, 256, 0, stream>>>(hv, WpT, bl, ylh, NV);
        k_mixed<<<nbE + nbV, 256, 0, stream>>>(ylh, eu, ev, hv, WaT, ba, mark,
                                               mv_out, me_out, NE, NV, nbE, nbV);
    } else {
        // minimal ws: stage fp16 YL in the (not yet written) mv region; serialize
        // edge pass (reads ylh) before mv pass (overwrites that region).
        u16* ylh = (u16*)mv_out;            // 12.8 MB <= 25.6 MB region
        k_vyl16<<<nbV, 256, 0, stream>>>(hv, WpT, bl, ylh, NV);
        k_mixed<<<nbE, 256, 0, stream>>>(ylh, eu, ev, hv, WaT, ba, mark,
                                         mv_out, me_out, NE, NV, nbE, 0);   // edges only
        k_mixed<<<nbV, 256, 0, stream>>>(ylh, eu, ev, hv, WaT, ba, mark,
                                         mv_out, me_out, NE, NV, 0, nbV);   // mv only
    }
}